// Round 1
// baseline (278.747 us; speedup 1.0000x reference)
//
#include <hip/hip_runtime.h>
#include <stdint.h>

typedef unsigned short u16;
typedef __attribute__((ext_vector_type(8))) short bf16x8;
typedef __attribute__((ext_vector_type(4))) float f32x4;
typedef __attribute__((ext_vector_type(8))) u16 u16x8;

#define NTOK 8192
#define DDIM 1024
#define HDIM 256
#define NEXP 16

__device__ __forceinline__ u16 f2bf(float f) {
  uint32_t u = __builtin_bit_cast(uint32_t, f);
  u += 0x7FFFu + ((u >> 16) & 1u);
  return (u16)(u >> 16);
}

// ---------------- fp32 -> bf16 bulk convert (n multiple of 2048*8) ----------
__global__ __launch_bounds__(256) void cvt_kernel(const float* __restrict__ in,
                                                  u16* __restrict__ out) {
  size_t i = ((size_t)blockIdx.x * 256 + threadIdx.x) * 8;
  const float4 a = *(const float4*)(in + i);
  const float4 b = *(const float4*)(in + i + 4);
  u16x8 o;
  o[0] = f2bf(a.x); o[1] = f2bf(a.y); o[2] = f2bf(a.z); o[3] = f2bf(a.w);
  o[4] = f2bf(b.x); o[5] = f2bf(b.y); o[6] = f2bf(b.z); o[7] = f2bf(b.w);
  *(u16x8*)(out + i) = o;
}

// ---------------- router: logits -> top4 -> softmax -> dense weights --------
__global__ __launch_bounds__(256) void router_kernel(const float* __restrict__ x,
                                                     const float* __restrict__ rw,
                                                     float* __restrict__ wgt) {
  const int wid = threadIdx.x >> 6, lane = threadIdx.x & 63;
  const int b = blockIdx.x * 4 + wid;
  double acc[NEXP];
#pragma unroll
  for (int e = 0; e < NEXP; ++e) acc[e] = 0.0;
  for (int d = lane; d < DDIM; d += 64) {
    float xv = x[(size_t)b * DDIM + d];
#pragma unroll
    for (int e = 0; e < NEXP; ++e) acc[e] += (double)xv * (double)rw[e * DDIM + d];
  }
#pragma unroll
  for (int e = 0; e < NEXP; ++e) {
#pragma unroll
    for (int off = 32; off > 0; off >>= 1) acc[e] += __shfl_xor(acc[e], off);
  }
  if (lane == 0) {
    float v[NEXP];
#pragma unroll
    for (int e = 0; e < NEXP; ++e) v[e] = (float)acc[e];
    int idx[4]; float tv[4];
    unsigned used = 0;
    for (int k = 0; k < 4; ++k) {
      int bi = 0; float bv = -3.4e38f;
      for (int e = 0; e < NEXP; ++e)
        if (!((used >> e) & 1u) && v[e] > bv) { bv = v[e]; bi = e; }
      idx[k] = bi; tv[k] = bv; used |= 1u << bi;
    }
    float m = tv[0];
    float w[4]; float s = 0.f;
    for (int k = 0; k < 4; ++k) { w[k] = expf(tv[k] - m); s += w[k]; }
    float o[NEXP];
#pragma unroll
    for (int e = 0; e < NEXP; ++e) o[e] = 0.f;
    for (int k = 0; k < 4; ++k) o[idx[k]] = w[k] / s;
    for (int e = 0; e < NEXP; ++e) wgt[(size_t)b * NEXP + e] = o[e];
  }
}

// ---------------- shared GEMM pieces (128x128 tile, BK=64, 4 waves) ---------
__device__ __forceinline__ void stage128x64(const u16* __restrict__ src, int ld,
                                            int kbase, uint8_t* dst, int tid) {
#pragma unroll
  for (int i = 0; i < 4; ++i) {
    int u = i * 256 + tid;
    int row = u >> 3, g = u & 7;
    uint4 v = *(const uint4*)(src + (size_t)row * ld + kbase + g * 8);
    *(uint4*)(dst + row * 128 + ((g ^ (row & 7)) << 4)) = v;
  }
}

__device__ __forceinline__ void mma_tile(const uint8_t* Ab, const uint8_t* Bb,
                                         f32x4 acc[4][4], int wm, int wn,
                                         int lrow, int lk) {
#pragma unroll
  for (int s = 0; s < 2; ++s) {
    bf16x8 af[4], bfr[4];
#pragma unroll
    for (int f = 0; f < 4; ++f) {
      int ar = wm * 64 + f * 16 + lrow;
      af[f] = *(const bf16x8*)(Ab + ar * 128 + ((((s << 2) | lk) ^ (ar & 7)) << 4));
      int br = wn * 64 + f * 16 + lrow;
      bfr[f] = *(const bf16x8*)(Bb + br * 128 + ((((s << 2) | lk) ^ (br & 7)) << 4));
    }
#pragma unroll
    for (int i = 0; i < 4; ++i)
#pragma unroll
      for (int j = 0; j < 4; ++j)
        acc[i][j] = __builtin_amdgcn_mfma_f32_16x16x32_bf16(af[i], bfr[j], acc[i][j], 0, 0, 0);
  }
}

// ---------------- GEMM1: H_e = relu(x @ W1e^T + b1e), bf16 out --------------
__global__ __launch_bounds__(256) void gemm1_kernel(const u16* __restrict__ xbf,
                                                    const u16* __restrict__ w1bf,
                                                    const float* __restrict__ b1,
                                                    u16* __restrict__ Hbuf,
                                                    int m0g, int CM) {
  __shared__ __align__(16) uint8_t smem[32768];
  uint8_t* Ab = smem;
  uint8_t* Bb = smem + 16384;
  const int e = blockIdx.z;
  const int n0 = blockIdx.y * 128;
  const int mb = blockIdx.x * 128;  // chunk-local token base
  const int tid = threadIdx.x;
  const int lane = tid & 63, wid = tid >> 6;
  const int wm = wid >> 1, wn = wid & 1;
  const int lrow = lane & 15, lk = lane >> 4;

  const u16* Asrc = xbf + (size_t)(m0g + mb) * DDIM;
  const u16* Bsrc = w1bf + (size_t)e * HDIM * DDIM + (size_t)n0 * DDIM;

  f32x4 acc[4][4];
#pragma unroll
  for (int i = 0; i < 4; ++i)
#pragma unroll
    for (int j = 0; j < 4; ++j) acc[i][j] = (f32x4){0.f, 0.f, 0.f, 0.f};

  for (int kt = 0; kt < DDIM / 64; ++kt) {
    stage128x64(Asrc, DDIM, kt * 64, Ab, tid);
    stage128x64(Bsrc, DDIM, kt * 64, Bb, tid);
    __syncthreads();
    mma_tile(Ab, Bb, acc, wm, wn, lrow, lk);
    __syncthreads();
  }
  // epilogue: bias + relu -> bf16 H
#pragma unroll
  for (int j = 0; j < 4; ++j) {
    int n = n0 + wn * 64 + j * 16 + lrow;
    float bias = b1[e * HDIM + n];
#pragma unroll
    for (int i = 0; i < 4; ++i) {
      int mloc = mb + wm * 64 + i * 16 + lk * 4;
#pragma unroll
      for (int r = 0; r < 4; ++r) {
        float h = fmaxf(acc[i][j][r] + bias, 0.f);
        Hbuf[((size_t)e * CM + mloc + r) * HDIM + n] = f2bf(h);
      }
    }
  }
}

// ------- GEMM2: out = sum_e w_e * relu(H_e @ W2e^T + b2e), fused over e -----
__global__ __launch_bounds__(256) void gemm2_kernel(const u16* __restrict__ Hbuf,
                                                    const u16* __restrict__ w2bf,
                                                    const float* __restrict__ b2,
                                                    const float* __restrict__ wgt,
                                                    float* __restrict__ out,
                                                    int m0g, int CM) {
  __shared__ __align__(16) uint8_t smem[40960];
  uint8_t* Ab = smem;
  uint8_t* Bb = smem + 16384;
  float* wLds = (float*)(smem + 32768);  // 128 rows x 16 experts
  const int n0 = blockIdx.y * 128;
  const int mb = blockIdx.x * 128;
  const int tid = threadIdx.x;
  const int lane = tid & 63, wid = tid >> 6;
  const int wm = wid >> 1, wn = wid & 1;
  const int lrow = lane & 15, lk = lane >> 4;

  for (int i = tid; i < 128 * NEXP; i += 256) {
    int rr = i >> 4, ee = i & 15;
    wLds[i] = wgt[(size_t)(m0g + mb + rr) * NEXP + ee];
  }

  f32x4 oacc[4][4];
#pragma unroll
  for (int i = 0; i < 4; ++i)
#pragma unroll
    for (int j = 0; j < 4; ++j) oacc[i][j] = (f32x4){0.f, 0.f, 0.f, 0.f};

  for (int e = 0; e < NEXP; ++e) {
    const u16* Asrc = Hbuf + ((size_t)e * CM + mb) * HDIM;
    const u16* Bsrc = w2bf + (size_t)e * DDIM * HDIM + (size_t)n0 * HDIM;
    f32x4 acc[4][4];
#pragma unroll
    for (int i = 0; i < 4; ++i)
#pragma unroll
      for (int j = 0; j < 4; ++j) acc[i][j] = (f32x4){0.f, 0.f, 0.f, 0.f};

    for (int kt = 0; kt < HDIM / 64; ++kt) {
      stage128x64(Asrc, HDIM, kt * 64, Ab, tid);
      stage128x64(Bsrc, HDIM, kt * 64, Bb, tid);
      __syncthreads();
      mma_tile(Ab, Bb, acc, wm, wn, lrow, lk);
      __syncthreads();
    }
    // epilogue: bias + relu, weight, accumulate
    float bias[4];
#pragma unroll
    for (int j = 0; j < 4; ++j) bias[j] = b2[e * DDIM + n0 + wn * 64 + j * 16 + lrow];
#pragma unroll
    for (int i = 0; i < 4; ++i) {
#pragma unroll
      for (int r = 0; r < 4; ++r) {
        float w = wLds[(wm * 64 + i * 16 + lk * 4 + r) * NEXP + e];
#pragma unroll
        for (int j = 0; j < 4; ++j) {
          float h = fmaxf(acc[i][j][r] + bias[j], 0.f);
          oacc[i][j][r] = fmaf(w, h, oacc[i][j][r]);
        }
      }
    }
  }
  // final store (f32)
#pragma unroll
  for (int i = 0; i < 4; ++i) {
#pragma unroll
    for (int r = 0; r < 4; ++r) {
      size_t gm = (size_t)(m0g + mb + wm * 64 + i * 16 + lk * 4 + r);
#pragma unroll
      for (int j = 0; j < 4; ++j) {
        int gn = n0 + wn * 64 + j * 16 + lrow;
        out[gm * DDIM + gn] = oacc[i][j][r];
      }
    }
  }
}

// ---------------------------------------------------------------------------
extern "C" void kernel_launch(void* const* d_in, const int* in_sizes, int n_in,
                              void* d_out, int out_size, void* d_ws, size_t ws_size,
                              hipStream_t stream) {
  const float* x = (const float*)d_in[0];
  const float* route_w = (const float*)d_in[1];
  const float* w1 = (const float*)d_in[2];
  const float* b1 = (const float*)d_in[3];
  const float* w2 = (const float*)d_in[4];
  const float* b2 = (const float*)d_in[5];
  float* out = (float*)d_out;

  uint8_t* ws = (uint8_t*)d_ws;
  float* wgt = (float*)ws;                                   // 8192*16*4 = 0.5 MB
  const size_t OFF_X = 524288;
  const size_t OFF_W1 = OFF_X + (size_t)NTOK * DDIM * 2;     // x bf16: 16 MB
  const size_t OFF_W2 = OFF_W1 + (size_t)NEXP * HDIM * DDIM * 2;  // 8 MB
  const size_t OFF_H = OFF_W2 + (size_t)NEXP * DDIM * HDIM * 2;   // 8 MB
  u16* xbf = (u16*)(ws + OFF_X);
  u16* w1bf = (u16*)(ws + OFF_W1);
  u16* w2bf = (u16*)(ws + OFF_W2);
  u16* Hbuf = (u16*)(ws + OFF_H);

  // chunk size over tokens based on remaining workspace
  size_t rem = (ws_size > OFF_H) ? (ws_size - OFF_H) : 0;
  long cmL = (long)(rem / ((size_t)NEXP * HDIM * 2));
  int CM = (int)(cmL & ~127L);
  if (CM > NTOK) CM = NTOK;
  if (CM < 128) CM = 128;

  cvt_kernel<<<dim3((NTOK * DDIM) / 2048), 256, 0, stream>>>(x, xbf);
  cvt_kernel<<<dim3((NEXP * HDIM * DDIM) / 2048), 256, 0, stream>>>(w1, w1bf);
  cvt_kernel<<<dim3((NEXP * DDIM * HDIM) / 2048), 256, 0, stream>>>(w2, w2bf);
  router_kernel<<<dim3(NTOK / 4), 256, 0, stream>>>(x, route_w, wgt);

  for (int c0 = 0; c0 < NTOK; c0 += CM) {
    int cm = (NTOK - c0 < CM) ? (NTOK - c0) : CM;
    dim3 g1(cm / 128, HDIM / 128, NEXP);
    gemm1_kernel<<<g1, 256, 0, stream>>>(xbf, w1bf, b1, Hbuf, c0, CM);
    dim3 g2(cm / 128, DDIM / 128);
    gemm2_kernel<<<g2, 256, 0, stream>>>(Hbuf, w2bf, b2, wgt, out, c0, CM);
  }
}